// Round 1
// baseline (545.404 us; speedup 1.0000x reference)
//
#include <hip/hip_runtime.h>

typedef __bf16 bf16_t;
typedef __bf16 bf16x8 __attribute__((ext_vector_type(8)));
typedef float  f32x4  __attribute__((ext_vector_type(4)));

#define ASYNC16(g, l) __builtin_amdgcn_global_load_lds( \
    (const __attribute__((address_space(1))) void*)(g), \
    (__attribute__((address_space(3))) void*)(l), 16, 0, 0)

// ---------------------------------------------------------------- cast all fp32 -> bf16
__global__ __launch_bounds__(256) void cast_all(
    const float* __restrict__ x, const float* __restrict__ wq,
    const float* __restrict__ wk, const float* __restrict__ wv,
    const float* __restrict__ wo,
    bf16_t* __restrict__ xb, bf16_t* __restrict__ wqkvb, bf16_t* __restrict__ wob)
{
  int i4 = blockIdx.x * 256 + threadIdx.x;   // 2,097,152 threads, 4 elems each
  int base = i4 * 4;
  const float* src; bf16_t* dst;
  if (base < 4194304) { src = x + base; dst = xb + base; }
  else {
    int j = base - 4194304;
    int w = j >> 20, o = j & 1048575;
    if      (w == 0) { src = wq + o; dst = wqkvb + o; }
    else if (w == 1) { src = wk + o; dst = wqkvb + (1 << 20) + o; }
    else if (w == 2) { src = wv + o; dst = wqkvb + (2 << 20) + o; }
    else             { src = wo + o; dst = wob + o; }
  }
  float4 v = *(const float4*)src;
  union { bf16_t h[4]; uint2 u; } pk;
  pk.h[0] = (bf16_t)v.x; pk.h[1] = (bf16_t)v.y;
  pk.h[2] = (bf16_t)v.z; pk.h[3] = (bf16_t)v.w;
  *(uint2*)dst = pk.u;
}

// ---------------------------------------------------------------- bias bucket table
// tbl[h*4096 + (rp+2047)] = rel_bias[bucket(rp)][h], rp in [-2047, 2047]
__global__ void build_tbl(const float* __restrict__ rel_bias, float* __restrict__ tbl)
{
  int i = blockIdx.x * 256 + threadIdx.x;
  if (i >= 4095 * 16) return;
  int rpi = i >> 4;            // rp + 2047
  int h = i & 15;
  int rp = rpi - 2047;
  int ret = rp >= 0 ? 16 : 0;
  int n = rp < 0 ? -rp : rp;
  int b;
  if (n < 8) b = ret + n;
  else {
    // log(n/8)/log(16)*8 == 2*log2(n) - 6 ; exact at integer boundaries in double
    double v = 2.0 * (log2((double)n) - 3.0);
    int bi = 8 + (int)v;
    b = ret + (bi < 15 ? bi : 15);
  }
  tbl[h * 4096 + rpi] = rel_bias[b * 16 + h];
}

// ---------------------------------------------------------------- GEMM: C[m,n] = sum_k A[m,k]*B[n,k]
// A:[M,K] bf16 row-major, B:[N,K] bf16 row-major (both K-contiguous). 128x128 tile, BK=32.
template<bool F32OUT>
__global__ __launch_bounds__(256) void gemm_bt(
    const bf16_t* __restrict__ A, const bf16_t* __restrict__ B,
    void* __restrict__ C, int M, int N, int K)
{
  __shared__ bf16_t As[128 * 32];
  __shared__ bf16_t Bs[128 * 32];
  const int t = threadIdx.x;
  const int w = t >> 6, l = t & 63, ln = l & 15, quad = l >> 4;
  const int wm = (w & 1) * 64, wn = (w >> 1) * 64;
  const int m0 = blockIdx.x * 128, n0 = blockIdx.y * 128;

  f32x4 acc[4][4] = {};

  const int rA = t >> 2, c8 = (t & 3) * 8;
  const bf16_t* Ag = A + (size_t)(m0 + rA) * K + c8;
  const bf16_t* Bg = B + (size_t)(n0 + rA) * K + c8;
  const size_t K64 = (size_t)64 * K;
  bf16_t* As0 = &As[t * 8];  bf16_t* As1 = &As[2048 + t * 8];
  bf16_t* Bs0 = &Bs[t * 8];  bf16_t* Bs1 = &Bs[2048 + t * 8];

  for (int kt = 0; kt < K; kt += 32) {
    ASYNC16(Ag + kt,       As0);
    ASYNC16(Ag + kt + K64, As1);
    ASYNC16(Bg + kt,       Bs0);
    ASYNC16(Bg + kt + K64, Bs1);
    __syncthreads();
    bf16x8 a[4], b[4];
#pragma unroll
    for (int mi = 0; mi < 4; ++mi)
      a[mi] = *(const bf16x8*)&As[(wm + mi * 16 + ln) * 32 + quad * 8];
#pragma unroll
    for (int ni = 0; ni < 4; ++ni)
      b[ni] = *(const bf16x8*)&Bs[(wn + ni * 16 + ln) * 32 + quad * 8];
#pragma unroll
    for (int mi = 0; mi < 4; ++mi)
#pragma unroll
      for (int ni = 0; ni < 4; ++ni)
        acc[mi][ni] = __builtin_amdgcn_mfma_f32_16x16x32_bf16(a[mi], b[ni], acc[mi][ni], 0, 0, 0);
    __syncthreads();
  }

#pragma unroll
  for (int mi = 0; mi < 4; ++mi)
#pragma unroll
    for (int ni = 0; ni < 4; ++ni) {
      int row = m0 + wm + mi * 16 + quad * 4;
      int col = n0 + wn + ni * 16 + ln;
#pragma unroll
      for (int j = 0; j < 4; ++j) {
        if (F32OUT) ((float*)C)[(size_t)(row + j) * N + col] = acc[mi][ni][j];
        else ((bf16_t*)C)[(size_t)(row + j) * N + col] = (bf16_t)acc[mi][ni][j];
      }
    }
}

// ---------------------------------------------------------------- flash attention
// qkv: [B*S, 3072] bf16 (Q|K|V per 1024 cols, head h at h*64). One block = (b,h,64 q-rows).
__global__ __launch_bounds__(256) void flash_attn(
    const bf16_t* __restrict__ qkv, const float* __restrict__ tbl,
    bf16_t* __restrict__ attn)
{
  __shared__ bf16_t Kt[64 * 64];       // [kcol][d]
  __shared__ bf16_t Vt[64 * 72];       // transposed: [d][kcol], stride 72 (16B aligned)
  __shared__ bf16_t Pt[4 * 16 * 72];   // per-wave P tile [16 q][64 k], stride 72
  const int t = threadIdx.x, w = t >> 6, l = t & 63, ln = l & 15, quad = l >> 4;
  const int q0 = blockIdx.x * 64, h = blockIdx.y, b = blockIdx.z;
  const int S = 2048, NH = 3072;

  // Q A-fragments for this wave's 16 rows (A[m=ln][k=quad*8+j])
  const bf16_t* Qp = qkv + (size_t)(b * S + q0 + w * 16 + ln) * NH + h * 64 + quad * 8;
  bf16x8 aq0 = *(const bf16x8*)Qp;
  bf16x8 aq1 = *(const bf16x8*)(Qp + 32);

  f32x4 o[4] = {};
  float mi[4], li[4];
#pragma unroll
  for (int j = 0; j < 4; ++j) { mi[j] = -1e30f; li[j] = 0.f; }

  const int sr = t >> 3, sc = (t & 7) * 8;   // staging: row sr (0..31), col sc
  const bf16_t* Kg = qkv + (size_t)(b * S) * NH + 1024 + h * 64 + sc;
  const bf16_t* Vg = qkv + (size_t)(b * S) * NH + 2048 + h * 64 + sc;
  const float* tb = tbl + h * 4096 + 2047 - (q0 + w * 16 + quad * 4);

  for (int kt = 0; kt < S; kt += 64) {
    __syncthreads();                               // prior tile fully consumed
    ASYNC16(Kg + (size_t)(kt + sr) * NH,      &Kt[t * 8]);
    ASYNC16(Kg + (size_t)(kt + sr + 32) * NH, &Kt[2048 + t * 8]);
#pragma unroll
    for (int r = 0; r < 2; ++r) {                  // V staged transposed
      union { uint4 u; bf16_t hh[8]; } cv;
      cv.u = *(const uint4*)(Vg + (size_t)(kt + sr + 32 * r) * NH);
#pragma unroll
      for (int i = 0; i < 8; ++i)
        Vt[(sc + i) * 72 + sr + 32 * r] = cv.hh[i];
    }
    __syncthreads();

    // S = Q K^T  (16 q x 64 k per wave)
    f32x4 s[4];
#pragma unroll
    for (int f = 0; f < 4; ++f) {
      const bf16_t* kp = &Kt[(f * 16 + ln) * 64 + quad * 8];
      bf16x8 b0 = *(const bf16x8*)kp;
      bf16x8 b1 = *(const bf16x8*)(kp + 32);
      f32x4 acc = {};
      acc = __builtin_amdgcn_mfma_f32_16x16x32_bf16(aq0, b0, acc, 0, 0, 0);
      acc = __builtin_amdgcn_mfma_f32_16x16x32_bf16(aq1, b1, acc, 0, 0, 0);
      s[f] = acc;
    }
    // scale + bias, tile row-max
    float xs[4][4], tm[4];
#pragma unroll
    for (int j = 0; j < 4; ++j) tm[j] = -1e30f;
#pragma unroll
    for (int f = 0; f < 4; ++f) {
      int kg = kt + f * 16 + ln;
#pragma unroll
      for (int j = 0; j < 4; ++j) {
        float xv = s[f][j] * 0.125f + __ldg(tb + kg - j);
        xs[f][j] = xv;
        tm[j] = fmaxf(tm[j], xv);
      }
    }
#pragma unroll
    for (int j = 0; j < 4; ++j)
#pragma unroll
      for (int mk = 1; mk < 16; mk <<= 1)
        tm[j] = fmaxf(tm[j], __shfl_xor(tm[j], mk));

    float al[4], rs[4];
#pragma unroll
    for (int j = 0; j < 4; ++j) {
      float mn = fmaxf(mi[j], tm[j]);
      al[j] = __expf(mi[j] - mn);
      mi[j] = mn;
      rs[j] = 0.f;
    }
    // P = exp(x - m), write to LDS in A-layout source (row=q, col=k)
    bf16_t* pw = &Pt[w * 1152 + (quad * 4) * 72 + ln];
#pragma unroll
    for (int f = 0; f < 4; ++f)
#pragma unroll
      for (int j = 0; j < 4; ++j) {
        float p = __expf(xs[f][j] - mi[j]);
        rs[j] += p;
        pw[j * 72 + f * 16] = (bf16_t)p;
      }
#pragma unroll
    for (int j = 0; j < 4; ++j) {
#pragma unroll
      for (int mk = 1; mk < 16; mk <<= 1)
        rs[j] += __shfl_xor(rs[j], mk);
      li[j] = li[j] * al[j] + rs[j];
    }
#pragma unroll
    for (int dt = 0; dt < 4; ++dt)
#pragma unroll
      for (int j = 0; j < 4; ++j)
        o[dt][j] *= al[j];

    // O += P V   (A = P from LDS, B = Vt rows are d, k-contiguous)
#pragma unroll
    for (int kk = 0; kk < 2; ++kk) {
      bf16x8 ap = *(const bf16x8*)&Pt[w * 1152 + ln * 72 + kk * 32 + quad * 8];
#pragma unroll
      for (int dt = 0; dt < 4; ++dt) {
        bf16x8 bv = *(const bf16x8*)&Vt[(dt * 16 + ln) * 72 + kk * 32 + quad * 8];
        o[dt] = __builtin_amdgcn_mfma_f32_16x16x32_bf16(ap, bv, o[dt], 0, 0, 0);
      }
    }
  }

  float inv[4];
#pragma unroll
  for (int j = 0; j < 4; ++j) inv[j] = 1.f / li[j];
  bf16_t* op = attn + (size_t)(b * S + q0 + w * 16 + quad * 4) * 1024 + h * 64 + ln;
#pragma unroll
  for (int dt = 0; dt < 4; ++dt)
#pragma unroll
    for (int j = 0; j < 4; ++j)
      op[(size_t)j * 1024 + dt * 16] = (bf16_t)(o[dt][j] * inv[j]);
}

// ---------------------------------------------------------------- past_bias writer
__global__ __launch_bounds__(256) void bias_out(const float* __restrict__ tbl,
                                                float* __restrict__ out1)
{
  int i = blockIdx.x * 256 + threadIdx.x;  // float4 index, 16,777,216 total
  int hq = i >> 9;                         // h*2048 + q
  int k4 = (i & 511) * 4;
  int h = hq >> 11, q = hq & 2047;
  const float* tp = tbl + (h << 12) + (k4 - q + 2047);
  float4 v;
  v.x = __ldg(tp);     v.y = __ldg(tp + 1);
  v.z = __ldg(tp + 2); v.w = __ldg(tp + 3);
  ((float4*)out1)[i] = v;
}

// ---------------------------------------------------------------- launch
extern "C" void kernel_launch(void* const* d_in, const int* in_sizes, int n_in,
                              void* d_out, int out_size, void* d_ws, size_t ws_size,
                              hipStream_t stream)
{
  const float* x  = (const float*)d_in[0];
  const float* wq = (const float*)d_in[1];
  const float* wk = (const float*)d_in[2];
  const float* wv = (const float*)d_in[3];
  const float* wo = (const float*)d_in[4];
  const float* rb = (const float*)d_in[5];
  float* out0 = (float*)d_out;          // attn_output [2,2048,1024]
  float* out1 = out0 + 4194304;         // past_bias  [1,16,2048,2048]

  char* ws = (char*)d_ws;
  bf16_t* xb    = (bf16_t*)(ws);                 //  8,388,608 B
  bf16_t* wqkvb = (bf16_t*)(ws + 8388608);       //  6,291,456 B
  bf16_t* wob   = (bf16_t*)(ws + 14680064);      //  2,097,152 B
  bf16_t* qkv   = (bf16_t*)(ws + 16777216);      // 25,165,824 B
  bf16_t* attnb = (bf16_t*)(ws + 41943040);      //  8,388,608 B
  float*  tbl   = (float*) (ws + 50331648);      //    262,144 B

  cast_all<<<8192, 256, 0, stream>>>(x, wq, wk, wv, wo, xb, wqkvb, wob);
  build_tbl<<<256, 256, 0, stream>>>(rb, tbl);
  gemm_bt<false><<<dim3(32, 24), 256, 0, stream>>>(xb, wqkvb, qkv, 4096, 3072, 1024);
  flash_attn<<<dim3(32, 16, 2), 256, 0, stream>>>(qkv, tbl, attnb);
  gemm_bt<true><<<dim3(32, 8), 256, 0, stream>>>(attnb, wob, out0, 4096, 1024, 1024);
  bias_out<<<65536, 256, 0, stream>>>(tbl, out1);
}

// Round 2
// 486.936 us; speedup vs baseline: 1.1201x; 1.1201x over previous
//
#include <hip/hip_runtime.h>

typedef __bf16 bf16_t;
typedef __bf16 bf16x8 __attribute__((ext_vector_type(8)));
typedef float  f32x4  __attribute__((ext_vector_type(4)));

#define ASYNC16(g, l) __builtin_amdgcn_global_load_lds( \
    (const __attribute__((address_space(1))) void*)(g), \
    (__attribute__((address_space(3))) void*)(l), 16, 0, 0)

#define MFMA(a, b, c) __builtin_amdgcn_mfma_f32_16x16x32_bf16(a, b, c, 0, 0, 0)

// ---------------------------------------------------------------- cast all fp32 -> bf16
__global__ __launch_bounds__(256) void cast_all(
    const float* __restrict__ x, const float* __restrict__ wq,
    const float* __restrict__ wk, const float* __restrict__ wv,
    const float* __restrict__ wo,
    bf16_t* __restrict__ xb, bf16_t* __restrict__ wqkvb, bf16_t* __restrict__ wob)
{
  int i4 = blockIdx.x * 256 + threadIdx.x;
  int base = i4 * 4;
  const float* src; bf16_t* dst;
  if (base < 4194304) { src = x + base; dst = xb + base; }
  else {
    int j = base - 4194304;
    int w = j >> 20, o = j & 1048575;
    if      (w == 0) { src = wq + o; dst = wqkvb + o; }
    else if (w == 1) { src = wk + o; dst = wqkvb + (1 << 20) + o; }
    else if (w == 2) { src = wv + o; dst = wqkvb + (2 << 20) + o; }
    else             { src = wo + o; dst = wob + o; }
  }
  float4 v = *(const float4*)src;
  union { bf16_t h[4]; uint2 u; } pk;
  pk.h[0] = (bf16_t)v.x; pk.h[1] = (bf16_t)v.y;
  pk.h[2] = (bf16_t)v.z; pk.h[3] = (bf16_t)v.w;
  *(uint2*)dst = pk.u;
}

// ---------------------------------------------------------------- bias tables
// tblB[h*4096 + rp+2047] = bias ;  tblE = bias * log2(e)  (flash works in exp2 domain)
__global__ void build_tbl(const float* __restrict__ rel_bias,
                          float* __restrict__ tblB, float* __restrict__ tblE)
{
  int i = blockIdx.x * 256 + threadIdx.x;
  if (i >= 4095 * 16) return;
  int rpi = i >> 4;
  int h = i & 15;
  int rp = rpi - 2047;
  int ret = rp >= 0 ? 16 : 0;
  int n = rp < 0 ? -rp : rp;
  int b;
  if (n < 8) b = ret + n;
  else {
    double v = 2.0 * (log2((double)n) - 3.0);   // log(n/8)/log(16)*8
    int bi = 8 + (int)v;
    b = ret + (bi < 15 ? bi : 15);
  }
  float v = rel_bias[b * 16 + h];
  tblB[h * 4096 + rpi] = v;
  tblE[h * 4096 + rpi] = v * 1.4426950408889634f;
}

// ---------------------------------------------------------------- QKV GEMM
// A:[4096,1024] xb, B:[3072,1024] wqkv. Q,K -> qk[token][2048]; V -> vt[b][h][d][s].
__global__ __launch_bounds__(256) void gemm_qkv(
    const bf16_t* __restrict__ A, const bf16_t* __restrict__ B,
    bf16_t* __restrict__ qk, bf16_t* __restrict__ vt)
{
  const int K = 1024;
  __shared__ bf16_t As[128 * 32];
  __shared__ bf16_t Bs[128 * 32];
  const int t = threadIdx.x;
  const int w = t >> 6, l = t & 63, ln = l & 15, quad = l >> 4;
  const int wm = (w & 1) * 64, wn = (w >> 1) * 64;
  const int m0 = blockIdx.x * 128, n0 = blockIdx.y * 128;

  f32x4 acc[4][4] = {};
  const int rA = t >> 2, c8 = (t & 3) * 8;
  const bf16_t* Ag = A + (size_t)(m0 + rA) * K + c8;
  const bf16_t* Bg = B + (size_t)(n0 + rA) * K + c8;
  const size_t K64 = (size_t)64 * K;
  bf16_t* As0 = &As[t * 8];  bf16_t* As1 = &As[2048 + t * 8];
  bf16_t* Bs0 = &Bs[t * 8];  bf16_t* Bs1 = &Bs[2048 + t * 8];

  for (int kt = 0; kt < K; kt += 32) {
    ASYNC16(Ag + kt,       As0);
    ASYNC16(Ag + kt + K64, As1);
    ASYNC16(Bg + kt,       Bs0);
    ASYNC16(Bg + kt + K64, Bs1);
    __syncthreads();
    bf16x8 a[4], b[4];
#pragma unroll
    for (int mi = 0; mi < 4; ++mi)
      a[mi] = *(const bf16x8*)&As[(wm + mi * 16 + ln) * 32 + quad * 8];
#pragma unroll
    for (int ni = 0; ni < 4; ++ni)
      b[ni] = *(const bf16x8*)&Bs[(wn + ni * 16 + ln) * 32 + quad * 8];
#pragma unroll
    for (int mi = 0; mi < 4; ++mi)
#pragma unroll
      for (int ni = 0; ni < 4; ++ni)
        acc[mi][ni] = MFMA(a[mi], b[ni], acc[mi][ni]);
    __syncthreads();
  }

  if (n0 >= 2048) {                       // V block -> transposed write
#pragma unroll
    for (int mi = 0; mi < 4; ++mi)
#pragma unroll
      for (int ni = 0; ni < 4; ++ni) {
        int col = n0 + wn + ni * 16 + ln - 2048;
        int hh = col >> 6, dd = col & 63;
        int row = m0 + wm + mi * 16 + quad * 4;
        int bb = row >> 11, ss = row & 2047;
        union { bf16_t h4[4]; uint2 u; } pk;
#pragma unroll
        for (int j = 0; j < 4; ++j) pk.h4[j] = (bf16_t)acc[mi][ni][j];
        *(uint2*)&vt[((size_t)(bb * 16 + hh) * 64 + dd) * 2048 + ss] = pk.u;
      }
  } else {                                // Q/K block -> row-major [token][2048]
#pragma unroll
    for (int mi = 0; mi < 4; ++mi)
#pragma unroll
      for (int ni = 0; ni < 4; ++ni) {
        int row = m0 + wm + mi * 16 + quad * 4;
        int col = n0 + wn + ni * 16 + ln;
#pragma unroll
        for (int j = 0; j < 4; ++j)
          qk[(size_t)(row + j) * 2048 + col] = (bf16_t)acc[mi][ni][j];
      }
  }
}

// ---------------------------------------------------------------- generic GEMM (f32 out)
__global__ __launch_bounds__(256) void gemm_bt_f32(
    const bf16_t* __restrict__ A, const bf16_t* __restrict__ B,
    float* __restrict__ C, int M, int N, int K)
{
  __shared__ bf16_t As[128 * 32];
  __shared__ bf16_t Bs[128 * 32];
  const int t = threadIdx.x;
  const int w = t >> 6, l = t & 63, ln = l & 15, quad = l >> 4;
  const int wm = (w & 1) * 64, wn = (w >> 1) * 64;
  const int m0 = blockIdx.x * 128, n0 = blockIdx.y * 128;

  f32x4 acc[4][4] = {};
  const int rA = t >> 2, c8 = (t & 3) * 8;
  const bf16_t* Ag = A + (size_t)(m0 + rA) * K + c8;
  const bf16_t* Bg = B + (size_t)(n0 + rA) * K + c8;
  const size_t K64 = (size_t)64 * K;
  bf16_t* As0 = &As[t * 8];  bf16_t* As1 = &As[2048 + t * 8];
  bf16_t* Bs0 = &Bs[t * 8];  bf16_t* Bs1 = &Bs[2048 + t * 8];

  for (int kt = 0; kt < K; kt += 32) {
    ASYNC16(Ag + kt,       As0);
    ASYNC16(Ag + kt + K64, As1);
    ASYNC16(Bg + kt,       Bs0);
    ASYNC16(Bg + kt + K64, Bs1);
    __syncthreads();
    bf16x8 a[4], b[4];
#pragma unroll
    for (int mi = 0; mi < 4; ++mi)
      a[mi] = *(const bf16x8*)&As[(wm + mi * 16 + ln) * 32 + quad * 8];
#pragma unroll
    for (int ni = 0; ni < 4; ++ni)
      b[ni] = *(const bf16x8*)&Bs[(wn + ni * 16 + ln) * 32 + quad * 8];
#pragma unroll
    for (int mi = 0; mi < 4; ++mi)
#pragma unroll
      for (int ni = 0; ni < 4; ++ni)
        acc[mi][ni] = MFMA(a[mi], b[ni], acc[mi][ni]);
    __syncthreads();
  }

#pragma unroll
  for (int mi = 0; mi < 4; ++mi)
#pragma unroll
    for (int ni = 0; ni < 4; ++ni) {
      int row = m0 + wm + mi * 16 + quad * 4;
      int col = n0 + wn + ni * 16 + ln;
#pragma unroll
      for (int j = 0; j < 4; ++j)
        C[(size_t)(row + j) * N + col] = acc[mi][ni][j];
    }
}

// ---------------------------------------------------------------- flash attention
// S^T layout: each lane owns ONE q row (q = q0 + w*16 + (lane&15)); scalar m/l state.
// qk: [4096][2048] (Q | K), vt: [2][16][64][2048] (V^T), tblE: log2-domain bias.
__global__ __launch_bounds__(256) void flash_attn(
    const bf16_t* __restrict__ qk, const bf16_t* __restrict__ vt,
    const float* __restrict__ tblE, bf16_t* __restrict__ attn)
{
  __shared__ __align__(16) bf16_t Kt[128 * 72];     // [k][d], pad 72
  __shared__ __align__(16) bf16_t Vs[64 * 136];     // [d][k], pad 136
  __shared__ __align__(16) bf16_t Pt[4 * 16 * 136]; // per-wave [q][k], pad 136
  const int t = threadIdx.x, w = t >> 6, l = t & 63, ln = l & 15, quad = l >> 4;
  const int q0 = blockIdx.x * 64, h = blockIdx.y, b = blockIdx.z;
  const int S = 2048;
  const int q = q0 + w * 16 + ln;

  // Q B-frag: B[n=ln][k=quad*8+j] (+32)
  const bf16_t* Qp = qk + (size_t)(b * S + q) * 2048 + h * 64 + quad * 8;
  bf16x8 bq0 = *(const bf16x8*)Qp;
  bf16x8 bq1 = *(const bf16x8*)(Qp + 32);

  f32x4 o[4] = {};
  float mi = -1e30f, li = 0.f;

  const bf16_t* Kg = qk + (size_t)(b * S) * 2048 + 1024 + h * 64;
  const bf16_t* Vg = vt + (size_t)(b * 16 + h) * 64 * 2048;
  const float* tb = tblE + h * 4096 + 2047 - q;

  const int kr = t >> 3, kc8 = (t & 7) * 8;     // K staging coords
  const int dr = t >> 4, vc8 = (t & 15) * 8;    // V staging coords

  for (int kt = 0; kt < S; kt += 128) {
    __syncthreads();
#pragma unroll
    for (int cc = 0; cc < 4; ++cc) {
      uint4 kv = *(const uint4*)(Kg + (size_t)(kt + kr + 32 * cc) * 2048 + kc8);
      uint4 vv = *(const uint4*)(Vg + (size_t)(dr + 16 * cc) * 2048 + kt + vc8);
      *(uint4*)&Kt[(kr + 32 * cc) * 72 + kc8] = kv;
      *(uint4*)&Vs[(dr + 16 * cc) * 136 + vc8] = vv;
    }
    __syncthreads();

    // S^T = K Q^T : D[m=k_local][n=q], A = K rows, B = Q rows
    f32x4 xs[8];
    float tm = -1e30f;
    const float* tbk = tb + kt;
#pragma unroll
    for (int f = 0; f < 8; ++f) {
      const bf16_t* kp = &Kt[(f * 16 + ln) * 72 + quad * 8];
      bf16x8 a0 = *(const bf16x8*)kp;
      bf16x8 a1 = *(const bf16x8*)(kp + 32);
      f32x4 acc = {};
      acc = MFMA(a0, bq0, acc);
      acc = MFMA(a1, bq1, acc);
#pragma unroll
      for (int j = 0; j < 4; ++j) {
        // log2-domain: score*0.125*log2e + bias*log2e
        float xv = fmaf(acc[j], 0.18033688011112042f,
                        __ldg(tbk + f * 16 + quad * 4 + j));
        xs[f][j] = xv;
        tm = fmaxf(tm, xv);
      }
    }
    tm = fmaxf(tm, __shfl_xor(tm, 16));
    tm = fmaxf(tm, __shfl_xor(tm, 32));
    float mn = fmaxf(mi, tm);
    float al = __builtin_amdgcn_exp2f(mi - mn);
    mi = mn;
    float rs = 0.f;
    bf16_t* pw = &Pt[w * 2176 + ln * 136];
#pragma unroll
    for (int f = 0; f < 8; ++f) {
      union { bf16_t h4[4]; uint2 u; } pk;
#pragma unroll
      for (int j = 0; j < 4; ++j) {
        float p = __builtin_amdgcn_exp2f(xs[f][j] - mn);
        rs += p;
        pk.h4[j] = (bf16_t)p;
      }
      *(uint2*)&pw[f * 16 + quad * 4] = pk.u;
    }
    rs += __shfl_xor(rs, 16);
    rs += __shfl_xor(rs, 32);
    li = li * al + rs;
#pragma unroll
    for (int dt = 0; dt < 4; ++dt)
#pragma unroll
      for (int j = 0; j < 4; ++j)
        o[dt][j] *= al;

    // O^T += V^T P^T : D[m=d][n=q], A = Vs rows (d), B = Pt rows (q)
#pragma unroll
    for (int kk = 0; kk < 4; ++kk) {
      bf16x8 bp = *(const bf16x8*)&Pt[w * 2176 + ln * 136 + kk * 32 + quad * 8];
#pragma unroll
      for (int dt = 0; dt < 4; ++dt) {
        bf16x8 av = *(const bf16x8*)&Vs[(dt * 16 + ln) * 136 + kk * 32 + quad * 8];
        o[dt] = MFMA(av, bp, o[dt]);
      }
    }
  }

  float inv = 1.f / li;
  bf16_t* op = attn + (size_t)(b * S + q) * 1024 + h * 64 + quad * 4;
#pragma unroll
  for (int dt = 0; dt < 4; ++dt) {
    union { bf16_t h4[4]; uint2 u; } pk;
#pragma unroll
    for (int j = 0; j < 4; ++j) pk.h4[j] = (bf16_t)(o[dt][j] * inv);
    *(uint2*)&op[dt * 16] = pk.u;
  }
}

// ---------------------------------------------------------------- past_bias writer
__global__ __launch_bounds__(256) void bias_out(const float* __restrict__ tbl,
                                                float* __restrict__ out1)
{
  int i = blockIdx.x * 256 + threadIdx.x;
  int hq = i >> 9;
  int k4 = (i & 511) * 4;
  int h = hq >> 11, q = hq & 2047;
  const float* tp = tbl + (h << 12) + (k4 - q + 2047);
  float4 v;
  v.x = __ldg(tp);     v.y = __ldg(tp + 1);
  v.z = __ldg(tp + 2); v.w = __ldg(tp + 3);
  ((float4*)out1)[i] = v;
}

// ---------------------------------------------------------------- launch
extern "C" void kernel_launch(void* const* d_in, const int* in_sizes, int n_in,
                              void* d_out, int out_size, void* d_ws, size_t ws_size,
                              hipStream_t stream)
{
  const float* x  = (const float*)d_in[0];
  const float* wq = (const float*)d_in[1];
  const float* wk = (const float*)d_in[2];
  const float* wv = (const float*)d_in[3];
  const float* wo = (const float*)d_in[4];
  const float* rb = (const float*)d_in[5];
  float* out0 = (float*)d_out;
  float* out1 = out0 + 4194304;

  char* ws = (char*)d_ws;
  bf16_t* xb    = (bf16_t*)(ws);                 // 8 MB (reused as attnb after gemm_qkv)
  bf16_t* wqkvb = (bf16_t*)(ws + 8388608);       // 6 MB
  bf16_t* wob   = (bf16_t*)(ws + 14680064);      // 2 MB
  bf16_t* qk    = (bf16_t*)(ws + 16777216);      // 16 MB  [4096][2048]
  bf16_t* vt    = (bf16_t*)(ws + 33554432);      // 8 MB   [2][16][64][2048]
  float*  tblB  = (float*)(ws + 41943040);       // 256 KB
  float*  tblE  = (float*)(ws + 42205184);       // 256 KB
  bf16_t* attnb = xb;                            // alias: xb dead after gemm_qkv

  cast_all<<<8192, 256, 0, stream>>>(x, wq, wk, wv, wo, xb, wqkvb, wob);
  build_tbl<<<256, 256, 0, stream>>>(rb, tblB, tblE);
  gemm_qkv<<<dim3(32, 24), 256, 0, stream>>>(xb, wqkvb, qk, vt);
  flash_attn<<<dim3(32, 16, 2), 256, 0, stream>>>(qk, vt, tblE, attnb);
  gemm_bt_f32<<<dim3(32, 8), 256, 0, stream>>>(attnb, wob, out0, 4096, 1024, 1024);
  bias_out<<<65536, 256, 0, stream>>>(tblB, out1);
}